// Round 6
// baseline (51.605 us; speedup 1.0000x reference)
//
#include <hip/hip_runtime.h>
#include <math.h>

#define NB       16
#define IMG      127
#define PLANE    (IMG * IMG)            // 16129
#define PN       4096
#define NTHREADS 512
#define PPT      8                      // output rows per thread
#define NROW     (2 * PPT + 1)          // 17 image rows per thread window

// index into upper-triangular symmetric 9x9 storage, requires p<=q
__device__ __forceinline__ constexpr int symidx(int p, int q) {
    return p * 9 - (p * (p - 1)) / 2 + (q - p);
}

// lane i <- lane i-1 (wave-wide shift); lane 0 <- 0 (bound_ctrl) = left zero-pad
__device__ __forceinline__ float dpp_wave_shr1(float v) {
    return __builtin_bit_cast(float, __builtin_amdgcn_update_dpp(
        0, __builtin_bit_cast(int, v), 0x138, 0xf, 0xf, true));
}

// 16-lane-group sum via 4 DPP adds; lanes 15 mod 16 hold their group's sum
__device__ __forceinline__ float wave_reduce16(float v) {
#define DPP_ADD(ctrl)                                                          \
    v += __builtin_bit_cast(float, __builtin_amdgcn_update_dpp(                \
             0, __builtin_bit_cast(int, v), (ctrl), 0xf, 0xf, true))
    DPP_ADD(0x111);   // row_shr:1
    DPP_ADD(0x112);   // row_shr:2
    DPP_ADD(0x114);   // row_shr:4
    DPP_ADD(0x118);   // row_shr:8
#undef DPP_ADD
    return v;
}

// launch_bounds arg2: empirically VGPR budget ~= 256/arg2 on this toolchain
// (r2/r3/r5: arg2=4 -> 64 VGPR cap + spill; r4: arg2=8 -> 32 VGPR cap).
// arg2=2 -> 128 VGPR budget; live set ~100 -> no spill, 4 waves/SIMD.
__global__ void __launch_bounds__(NTHREADS, 2)
scann_fused(const float* __restrict__ x,
            const float* __restrict__ Wq, const float* __restrict__ bq,
            const float* __restrict__ Wk, const float* __restrict__ bk,
            const float* __restrict__ Wv, const float* __restrict__ bv,
            const float* __restrict__ Wo, const float* __restrict__ bo,
            float* __restrict__ out)
{
    __shared__ float red[32 * 54];              // 16-lane-group partials
    __shared__ float Msh[45];                   // Gram (upper tri)
    __shared__ float msh[9];                    // column sums
    __shared__ float MW[81];                    // M @ Wq
    __shared__ float Wq_s[81], Wk_s[81], Wv_s[81];
    __shared__ float bq_s[9], bk_s[9], bv_s[9], Wo_s[9];
    __shared__ float en[81], at[81], wt[9], u_s[9];
    __shared__ float c_s, bo_sh;

    const int bg  = blockIdx.x;                 // b*64 + g
    const int g   = bg & 63;
    const int tid = threadIdx.x;
    const int ow  = tid & 63;                   // lane = output col
    const int wv  = tid >> 6;                   // wave id 0..7
    const int oh0 = wv * PPT;                   // first output row of this thread

    const float* __restrict__ xp = x + (size_t)bg * PLANE;

    // stage tiny weights (disjoint thread ranges); consumed after barrier 1
    if (tid < 81) {
        Wq_s[tid] = Wq[g * 81 + tid];
        Wk_s[tid] = Wk[g * 81 + tid];
        Wv_s[tid] = Wv[g * 81 + tid];
    } else if (tid >= 128 && tid < 137) {
        const int i = tid - 128;
        bq_s[i] = bq[g * 9 + i];
        bk_s[i] = bk[g * 9 + i];
        bv_s[i] = bv[g * 9 + i];
        Wo_s[i] = Wo[g * 9 + i];
    } else if (tid == 192) {
        bo_sh = bo[g];
    }

    const bool c2   = (ow < 63);                // lane 63's odd col (127) is pad
    const int  col0 = 2 * ow;                   // even col, always valid (<=126)
    const int  col1 = c2 ? 2 * ow + 1 : 126;    // clamped: safe addr, masked below
    const int  ih0  = oh0 * 2 - 1;              // first image row of window

    // ---- load the 17-row x window into registers (x read EXACTLY once) ----
    float e0[NROW], e1[NROW];
    #pragma unroll
    for (int r = 0; r < NROW; ++r) {
        const int ih = ih0 + r;                 // wave-uniform
        float a = 0.f, b = 0.f;
        if ((unsigned)ih < (unsigned)IMG) {     // no load issued for pad rows
            a = xp[ih * IMG + col0];
            const float t = xp[ih * IMG + col1];
            b = c2 ? t : 0.f;
        }
        e0[r] = a; e1[r] = b;
    }

    // ---- phase 1: Gram (45) + column sums (9), all from registers ----
    float acc[45], mm[9];
    #pragma unroll
    for (int i = 0; i < 45; ++i) acc[i] = 0.f;
    #pragma unroll
    for (int i = 0; i < 9; ++i)  mm[i] = 0.f;

    #pragma unroll
    for (int k = 0; k < PPT; ++k) {
        float v[9];
        #pragma unroll
        for (int r = 0; r < 3; ++r) {
            const int rr = 2 * k + r;
            v[3 * r + 0] = dpp_wave_shr1(e1[rr]);   // col 2ow-1 (CSE'd across k)
            v[3 * r + 1] = e0[rr];                  // col 2ow
            v[3 * r + 2] = e1[rr];                  // col 2ow+1
        }
        int idx = 0;
        #pragma unroll
        for (int p = 0; p < 9; ++p) {
            mm[p] += v[p];
            #pragma unroll
            for (int q = p; q < 9; ++q)
                acc[idx++] += v[p] * v[q];
        }
    }

    // 16-lane-group DPP reduce, 32 partial slots to LDS
    #pragma unroll
    for (int i = 0; i < 45; ++i) acc[i] = wave_reduce16(acc[i]);
    #pragma unroll
    for (int i = 0; i < 9; ++i)  mm[i] = wave_reduce16(mm[i]);
    if ((tid & 15) == 15) {
        const int slot = tid >> 4;              // 0..31
        #pragma unroll
        for (int i = 0; i < 45; ++i) red[slot * 54 + i]      = acc[i];
        #pragma unroll
        for (int i = 0; i < 9; ++i)  red[slot * 54 + 45 + i] = mm[i];
    }
    __syncthreads();                            // barrier 1

    // ---- tiny math, all inside wave 0 (in-wave LDS program order) ----
    if (wv == 0) {
        const int lane = ow;
        if (lane < 54) {                        // cross-group final reduce
            float s = 0.f;
            #pragma unroll
            for (int w = 0; w < 32; ++w) s += red[w * 54 + lane];
            if (lane < 45) Msh[lane]      = s;
            else           msh[lane - 45] = s;
        }
        #pragma unroll
        for (int r = 0; r < 2; ++r) {           // MW = M @ Wq (81 entries)
            const int e = lane + r * 64;
            if (e < 81) {
                const int p = e / 9, t = e % 9;
                float a2 = 0.f;
                #pragma unroll
                for (int q = 0; q < 9; ++q) {
                    const int a_ = p < q ? p : q, b_ = p < q ? q : p;
                    a2 += Msh[symidx(a_, b_)] * Wq_s[q * 9 + t];
                }
                MW[e] = a2;
            }
        }
        #pragma unroll
        for (int r = 0; r < 2; ++r) {           // energy
            const int e = lane + r * 64;
            if (e < 81) {
                const int s = e / 9, t = e % 9;
                float km = 0.f, qm = 0.f, a2 = 0.f;
                #pragma unroll
                for (int p = 0; p < 9; ++p) {
                    km += Wk_s[p * 9 + s] * msh[p];
                    qm += Wq_s[p * 9 + t] * msh[p];
                    a2 += Wk_s[p * 9 + s] * MW[p * 9 + t];
                }
                en[e] = a2 + (float)PN * bk_s[s] * bq_s[t] + km * bq_s[t] + bk_s[s] * qm;
            }
        }
        if (lane < 9) {                         // softmax over t per row s
            const int s = lane;
            float mx = en[s * 9];
            #pragma unroll
            for (int t = 1; t < 9; ++t) mx = fmaxf(mx, en[s * 9 + t]);
            float ex[9], sum = 0.f;
            #pragma unroll
            for (int t = 0; t < 9; ++t) { ex[t] = expf(en[s * 9 + t] - mx); sum += ex[t]; }
            const float inv = 1.f / sum;
            #pragma unroll
            for (int t = 0; t < 9; ++t) at[s * 9 + t] = ex[t] * inv;
        }
        if (lane < 9) {                         // wt[t] = sum_s attn[s,t] * Wo[s]
            const int t = lane;
            float w = 0.f;
            #pragma unroll
            for (int s = 0; s < 9; ++s) w += at[s * 9 + t] * Wo_s[s];
            wt[t] = w;
        }
        if (lane < 9) {                         // u[p] = sum_t Wv[p,t] * wt[t]
            const int p = lane;
            float uu = 0.f;
            #pragma unroll
            for (int t = 0; t < 9; ++t) uu += Wv_s[p * 9 + t] * wt[t];
            u_s[p] = uu;
        }
        if (lane == 12) {                       // c = bv.wt + bo
            float cc = bo_sh;
            #pragma unroll
            for (int t = 0; t < 9; ++t) cc += bv_s[t] * wt[t];
            c_s = cc;
        }
    }
    __syncthreads();                            // barrier 2

    // ---- phase 2: out = t . u + c, straight from the register window ----
    float ur[9];
    #pragma unroll
    for (int i = 0; i < 9; ++i) ur[i] = u_s[i];
    const float cc = c_s;
    float* __restrict__ op = out + (size_t)bg * PN;

    #pragma unroll
    for (int k = 0; k < PPT; ++k) {
        float o = cc;
        #pragma unroll
        for (int r = 0; r < 3; ++r) {
            const int rr = 2 * k + r;
            o += dpp_wave_shr1(e1[rr]) * ur[3 * r + 0];
            o += e0[rr]                * ur[3 * r + 1];
            o += e1[rr]                * ur[3 * r + 2];
        }
        op[(oh0 + k) * 64 + ow] = o;
    }
}

extern "C" void kernel_launch(void* const* d_in, const int* in_sizes, int n_in,
                              void* d_out, int out_size, void* d_ws, size_t ws_size,
                              hipStream_t stream) {
    (void)in_sizes; (void)n_in; (void)d_ws; (void)ws_size; (void)out_size;
    const float* x  = (const float*)d_in[0];
    const float* Wq = (const float*)d_in[1];
    const float* bq = (const float*)d_in[2];
    const float* Wk = (const float*)d_in[3];
    const float* bk = (const float*)d_in[4];
    const float* Wv = (const float*)d_in[5];
    const float* bv = (const float*)d_in[6];
    const float* Wo = (const float*)d_in[7];
    const float* bo = (const float*)d_in[8];
    float* out = (float*)d_out;

    dim3 grid(NB * 64), block(NTHREADS);
    hipLaunchKernelGGL(scann_fused, grid, block, 0, stream,
                       x, Wq, bq, Wk, bk, Wv, bv, Wo, bo, out);
}

// Round 8
// 45.765 us; speedup vs baseline: 1.1276x; 1.1276x over previous
//
#include <hip/hip_runtime.h>
#include <math.h>

#define NB       16
#define IMG      127
#define PLANE    (IMG * IMG)            // 16129
#define PN       4096
#define NTHREADS 512
#define PPT      8                      // output rows per thread
#define NROW     (2 * PPT + 1)          // 17 image rows per thread window

#define GLOBAL_AS __attribute__((address_space(1)))
#define LDS_AS    __attribute__((address_space(3)))

// index into upper-triangular symmetric 9x9 storage, requires p<=q
__device__ __forceinline__ constexpr int symidx(int p, int q) {
    return p * 9 - (p * (p - 1)) / 2 + (q - p);
}

// lane i <- lane i-1 (wave-wide shift); lane 0 <- 0 (bound_ctrl) = left zero-pad
__device__ __forceinline__ float dpp_wave_shr1(float v) {
    return __builtin_bit_cast(float, __builtin_amdgcn_update_dpp(
        0, __builtin_bit_cast(int, v), 0x138, 0xf, 0xf, true));
}

// full 64-lane sum via 6 DPP adds (VALU only); result valid in lane 63
__device__ __forceinline__ float wave_reduce_full(float v) {
#define DPP_ADD(ctrl)                                                          \
    v += __builtin_bit_cast(float, __builtin_amdgcn_update_dpp(                \
             0, __builtin_bit_cast(int, v), (ctrl), 0xf, 0xf, true))
    DPP_ADD(0x111);   // row_shr:1
    DPP_ADD(0x112);   // row_shr:2
    DPP_ADD(0x114);   // row_shr:4
    DPP_ADD(0x118);   // row_shr:8
    DPP_ADD(0x142);   // row_bcast:15
    DPP_ADD(0x143);   // row_bcast:31 -> lane63 = sum(0..63)
#undef DPP_ADD
    return v;
}

// Intra-wave cross-lane LDS exchange fence: prevents the compiler from
// reordering ds ops across it (r7 failed without this — lane A's read of
// lane B's LDS write is a data race the scheduler may legally invert).
#define XLANE_FENCE() __builtin_amdgcn_wave_barrier()

// launch_bounds arg2 ~ VGPR budget 256/arg2 (r2..r6 evidence): arg2=2 -> 128.
__global__ void __launch_bounds__(NTHREADS, 2)
scann_fused(const float* __restrict__ x,
            const float* __restrict__ Wq, const float* __restrict__ bq,
            const float* __restrict__ Wk, const float* __restrict__ bk,
            const float* __restrict__ Wv, const float* __restrict__ bv,
            const float* __restrict__ Wo, const float* __restrict__ bo,
            float* __restrict__ out)
{
    __shared__ float plane[PLANE];              // 64516 B channel plane
    __shared__ float red[8 * 54];               // per-wave Gram partials
    __shared__ float Msh[45];                   // Gram (upper tri)
    __shared__ float msh[9];                    // column sums
    __shared__ float MW[81];                    // M @ Wq
    __shared__ float Wq_s[81], Wk_s[81], Wv_s[81];
    __shared__ float bq_s[9], bk_s[9], bv_s[9], Wo_s[9];
    __shared__ float en[81], at[81], wt[9], u_s[9];
    __shared__ float c_s, bo_sh;

    const int bg  = blockIdx.x;                 // b*64 + g
    const int g   = bg & 63;
    const int tid = threadIdx.x;
    const int ow  = tid & 63;                   // lane = output col
    const int wv  = tid >> 6;                   // wave id 0..7
    const int oh0 = wv * PPT;                   // first output row of this thread

    const float* __restrict__ xp = x + (size_t)bg * PLANE;

    // ---- stage plane (r3-proven): peel, 7 x width-16 async rounds, tail ----
    const int a0 = (4 - (bg & 3)) & 3;          // head floats to reach 16B alignment
    if (tid < a0) plane[tid] = xp[tid];
    #pragma unroll
    for (int j = 0; j < 7; ++j) {
        __builtin_amdgcn_global_load_lds(
            (const GLOBAL_AS void*)(xp + a0 + (j * NTHREADS + tid) * 4),
            (LDS_AS void*)(&plane[a0 + (j * NTHREADS + wv * 64) * 4]), 16, 0, 0);
    }
    {
        const int base = a0 + 7 * NTHREADS * 4;         // a0 + 14336
        const int cnt  = PLANE - base;                  // 1790..1793
        for (int i = tid; i < cnt; i += NTHREADS)
            plane[base + i] = xp[base + i];
    }

    // stage tiny weights (disjoint thread ranges)
    if (tid < 81) {
        Wq_s[tid] = Wq[g * 81 + tid];
        Wk_s[tid] = Wk[g * 81 + tid];
        Wv_s[tid] = Wv[g * 81 + tid];
    } else if (tid >= 128 && tid < 137) {
        const int i = tid - 128;
        bq_s[i] = bq[g * 9 + i];
        bk_s[i] = bk[g * 9 + i];
        bv_s[i] = bv[g * 9 + i];
        Wo_s[i] = Wo[g * 9 + i];
    } else if (tid == 192) {
        bo_sh = bo[g];
    }
    __syncthreads();                            // barrier 1: plane + weights ready

    const bool c2  = (ow < 63);                 // lane 63's odd col (127) is pad
    const int  ih0 = oh0 * 2 - 1;               // first image row of window

    // ---- window LDS -> registers (17 rows x even/odd); no OOB reads ----
    float e0[NROW], e1[NROW];
    #pragma unroll
    for (int r = 0; r < NROW; ++r) {
        const int ih = ih0 + r;                 // wave-uniform
        float a = 0.f, b = 0.f;
        if ((unsigned)ih < (unsigned)IMG) {
            const int wa = ih * IMG + 2 * ow;
            a = plane[wa];
            if (c2) b = plane[wa + 1];          // exec-masked: lane 63 never reads
        }
        e0[r] = a; e1[r] = b;
    }

    // ---- phase 1: Gram (45) + column sums (9), all from registers ----
    float acc[45], mm[9];
    #pragma unroll
    for (int i = 0; i < 45; ++i) acc[i] = 0.f;
    #pragma unroll
    for (int i = 0; i < 9; ++i)  mm[i] = 0.f;

    #pragma unroll
    for (int k = 0; k < PPT; ++k) {
        float v[9];
        #pragma unroll
        for (int r = 0; r < 3; ++r) {
            const int rr = 2 * k + r;
            v[3 * r + 0] = dpp_wave_shr1(e1[rr]);   // col 2ow-1
            v[3 * r + 1] = e0[rr];                  // col 2ow
            v[3 * r + 2] = e1[rr];                  // col 2ow+1
        }
        int idx = 0;
        #pragma unroll
        for (int p = 0; p < 9; ++p) {
            mm[p] += v[p];
            #pragma unroll
            for (int q = p; q < 9; ++q)
                acc[idx++] += v[p] * v[q];
        }
    }

    // full-wave DPP reduce; lane 63 writes this wave's 54 partials
    #pragma unroll
    for (int i = 0; i < 45; ++i) acc[i] = wave_reduce_full(acc[i]);
    #pragma unroll
    for (int i = 0; i < 9; ++i)  mm[i] = wave_reduce_full(mm[i]);
    if (ow == 63) {
        #pragma unroll
        for (int i = 0; i < 45; ++i) red[wv * 54 + i]      = acc[i];
        #pragma unroll
        for (int i = 0; i < 9; ++i)  red[wv * 54 + 45 + i] = mm[i];
    }
    __syncthreads();                            // barrier 2: red[] complete

    // ---- tiny math: wave 0 only, with explicit intra-wave exchange fences ----
    if (wv == 0) {
        const int lane = ow;
        if (lane < 54) {                        // cross-wave final reduce
            float s = 0.f;
            #pragma unroll
            for (int w = 0; w < 8; ++w) s += red[w * 54 + lane];
            if (lane < 45) Msh[lane]      = s;
            else           msh[lane - 45] = s;
        }
        XLANE_FENCE();
        #pragma unroll
        for (int r = 0; r < 2; ++r) {           // MW = M @ Wq (81 entries)
            const int e = lane + r * 64;
            if (e < 81) {
                const int p = e / 9, t = e % 9;
                float a2 = 0.f;
                #pragma unroll
                for (int q = 0; q < 9; ++q) {
                    const int a_ = p < q ? p : q, b_ = p < q ? q : p;
                    a2 += Msh[symidx(a_, b_)] * Wq_s[q * 9 + t];
                }
                MW[e] = a2;
            }
        }
        XLANE_FENCE();
        #pragma unroll
        for (int r = 0; r < 2; ++r) {           // energy
            const int e = lane + r * 64;
            if (e < 81) {
                const int s = e / 9, t = e % 9;
                float km = 0.f, qm = 0.f, a2 = 0.f;
                #pragma unroll
                for (int p = 0; p < 9; ++p) {
                    km += Wk_s[p * 9 + s] * msh[p];
                    qm += Wq_s[p * 9 + t] * msh[p];
                    a2 += Wk_s[p * 9 + s] * MW[p * 9 + t];
                }
                en[e] = a2 + (float)PN * bk_s[s] * bq_s[t] + km * bq_s[t] + bk_s[s] * qm;
            }
        }
        XLANE_FENCE();
        if (lane < 9) {                         // softmax over t per row s
            const int s = lane;
            float mx = en[s * 9];
            #pragma unroll
            for (int t = 1; t < 9; ++t) mx = fmaxf(mx, en[s * 9 + t]);
            float ex[9], sum = 0.f;
            #pragma unroll
            for (int t = 0; t < 9; ++t) { ex[t] = expf(en[s * 9 + t] - mx); sum += ex[t]; }
            const float inv = 1.f / sum;
            #pragma unroll
            for (int t = 0; t < 9; ++t) at[s * 9 + t] = ex[t] * inv;
        }
        XLANE_FENCE();
        if (lane < 9) {                         // wt[t] = sum_s attn[s,t] * Wo[s]
            const int t = lane;
            float w = 0.f;
            #pragma unroll
            for (int s = 0; s < 9; ++s) w += at[s * 9 + t] * Wo_s[s];
            wt[t] = w;
        }
        XLANE_FENCE();
        if (lane < 9) {                         // u[p] = sum_t Wv[p,t] * wt[t]
            const int p = lane;
            float uu = 0.f;
            #pragma unroll
            for (int t = 0; t < 9; ++t) uu += Wv_s[p * 9 + t] * wt[t];
            u_s[p] = uu;
        }
        if (lane == 12) {                       // c = bv.wt + bo
            float cc = bo_sh;
            #pragma unroll
            for (int t = 0; t < 9; ++t) cc += bv_s[t] * wt[t];
            c_s = cc;
        }
    }
    __syncthreads();                            // barrier 3: u_s/c_s ready

    // ---- phase 2: out = t . u + c, straight from the register window ----
    float ur[9];
    #pragma unroll
    for (int i = 0; i < 9; ++i) ur[i] = u_s[i];
    const float cc = c_s;
    float* __restrict__ op = out + (size_t)bg * PN;

    #pragma unroll
    for (int k = 0; k < PPT; ++k) {
        float o = cc;
        #pragma unroll
        for (int r = 0; r < 3; ++r) {
            const int rr = 2 * k + r;
            o += dpp_wave_shr1(e1[rr]) * ur[3 * r + 0];
            o += e0[rr]                * ur[3 * r + 1];
            o += e1[rr]                * ur[3 * r + 2];
        }
        op[(oh0 + k) * 64 + ow] = o;
    }
}

extern "C" void kernel_launch(void* const* d_in, const int* in_sizes, int n_in,
                              void* d_out, int out_size, void* d_ws, size_t ws_size,
                              hipStream_t stream) {
    (void)in_sizes; (void)n_in; (void)d_ws; (void)ws_size; (void)out_size;
    const float* x  = (const float*)d_in[0];
    const float* Wq = (const float*)d_in[1];
    const float* bq = (const float*)d_in[2];
    const float* Wk = (const float*)d_in[3];
    const float* bk = (const float*)d_in[4];
    const float* Wv = (const float*)d_in[5];
    const float* bv = (const float*)d_in[6];
    const float* Wo = (const float*)d_in[7];
    const float* bo = (const float*)d_in[8];
    float* out = (float*)d_out;

    dim3 grid(NB * 64), block(NTHREADS);
    hipLaunchKernelGGL(scann_fused, grid, block, 0, stream,
                       x, Wq, bq, Wk, bk, Wv, bv, Wo, bo, out);
}